// Round 17
// baseline (187.140 us; speedup 1.0000x reference)
//
#include <hip/hip_runtime.h>
#include <hip/hip_bf16.h>
#include <cstdint>
#include <cstddef>

// B=512, K=32, D=2048, H=512, Z=64; M_all = 16896; M_nn = 16384
#define DEV __device__ __forceinline__

typedef __bf16 bf16;
typedef __bf16 bf16x8 __attribute__((ext_vector_type(8)));
typedef float f32x4 __attribute__((ext_vector_type(4)));

DEV f32x4 mfma16(bf16x8 a, bf16x8 b, f32x4 c) {
  return __builtin_amdgcn_mfma_f32_16x16x32_bf16(a, b, c, 0, 0, 0);
}

DEV void glds16(const void* g, void* l) {
  __builtin_amdgcn_global_load_lds(
      (const __attribute__((address_space(1))) void*)g,
      (__attribute__((address_space(3))) void*)l, 16, 0, 0);
}

// ---------------------------------------------------------------------------
// Stage ROWSx64 bf16 tile (128B rows) -> LDS, XOR swizzle ((row&7)<<4) via
// pre-swizzled global source column; LDS dest linear (glds requirement).
// ---------------------------------------------------------------------------
template<int ROWS, int NT>
DEV void stage_tile(const bf16* __restrict__ src, int ld, int row0, int k0,
                    unsigned char* lds, int tid) {
  constexpr int CALLS = (ROWS * 128) / (NT * 16);
  const int wid = tid >> 6, lane = tid & 63;
#pragma unroll
  for (int c = 0; c < CALLS; ++c) {
    const int obase = c * (NT * 16) + wid * 1024;   // wave-uniform
    const int o = obase + lane * 16;
    const int row = o >> 7;
    const int scb = (o & 127) ^ ((row & 7) << 4);
    glds16(src + (size_t)(row0 + row) * ld + k0 + (scb >> 1), lds + obase);
  }
}

// ---------------------------------------------------------------------------
// Stage ROWSx64 f32 tile (256B rows) -> LDS, 16B-granular XOR swizzle
// ((row&7)<<4). Source column pre-swizzled; LDS dest linear (glds req).
// ---------------------------------------------------------------------------
template<int ROWS, int NT>
DEV void stage_tile_f32(const float* __restrict__ src, int ld, int row0, int k0,
                        unsigned char* lds, int tid) {
  constexpr int CALLS = (ROWS * 256) / (NT * 16);
  const int wid = tid >> 6, lane = tid & 63;
#pragma unroll
  for (int c = 0; c < CALLS; ++c) {
    const int obase = c * (NT * 16) + wid * 1024;   // wave-uniform
    const int o = obase + lane * 16;
    const int row = o >> 8;
    const int scb = (o & 255) ^ ((row & 7) << 4);
    glds16(src + (size_t)(row0 + row) * ld + k0 + (scb >> 2), lds + obase);
  }
}

// ---------------------------------------------------------------------------
// MFMA GEMM: C[M,N] = A[M,K] @ Bt[N,K]^T, bf16 LDS tiles, f32 accum. BK=64.
// AF32=1 (GEMM1): A is f32 [Af rows<512; Af2 rest], staged RAW via glds;
//   fragment load reads two f32x4 + casts to bf16 in-register. x read once.
// R24 model (16 rounds): the glds->LDS staging family saturates at ~8-13 TB/s
//   aggregate delivery (needs residency >= 2-3); time ~ staged_bytes / rate.
//   GEMM1 (AF32 128x128, 823 MB, grid 528) = the measured family optimum.
// R25 (this round): GEMM6 re-tiled BM=128/BN=256/512thr — staged bytes
//   537 -> 402 MB (A-panels 16 -> 8), grid (8,128)=1024, LDS 48KB (R~3).
//   MODE-5 epilogue generalized over TPR=BN/16 (16 cols/thread, 32 rows/pass,
//   TPR-lane shuffle reduce).
// MODE: 0 relu->bf16; 1 f32+bias; 2 both; 4 mask by hc>0 -> bf16;
//       5 fused loss (nloss/warg via LDS C re-layout, f32 x reads).
// ---------------------------------------------------------------------------
template<int BM, int BN, int WM, int WN, int MODE, int AF32, int MINW = 2>
__global__ __launch_bounds__(WM*WN*64, MINW) void gemm_kernel(
    const bf16* __restrict__ A, const float* __restrict__ Af,
    const float* __restrict__ Af2,
    const bf16* __restrict__ Bt, const float* __restrict__ bias,
    int M, int N, int K,
    float* __restrict__ out32, bf16* __restrict__ out16,
    const float* __restrict__ hc, const float* __restrict__ recon,
    float* __restrict__ nloss, float* __restrict__ warg)
{
  constexpr int NT = WM * WN * 64;
  constexpr int FM = (BM / WM) / 16;
  constexpr int FN = (BN / WN) / 16;
  __shared__ __align__(16) unsigned char smem[AF32 ? (BM * 256 + BN * 128)
                                                   : (BM + BN) * 128];

  const int tid = threadIdx.x, lane = tid & 63, wid = tid >> 6;
  const int wm = wid / WN, wn = wid % WN;
  const int wm0 = wm * (BM / WM), wn0 = wn * (BN / WN);

  // XCD-chunked bijective remap (hw id%8 = XCD).
  int bx = blockIdx.x, by = blockIdx.y;
  {
    const int gx = gridDim.x;
    const int nwg = gx * gridDim.y;
    if ((nwg & 7) == 0) {
      const int fid = by * gx + bx;
      const int cpx = nwg >> 3;
      const int w = (fid & 7) * cpx + (fid >> 3);
      bx = w % gx; by = w / gx;
    }
  }
  const int i0 = by * BM, j0 = bx * BN;
  const int l15 = lane & 15, lg = lane >> 4;

  f32x4 acc[FM][FN] = {};

  int arow[FM], brow[FN];
#pragma unroll
  for (int mi = 0; mi < FM; ++mi) arow[mi] = wm0 + mi * 16 + l15;
#pragma unroll
  for (int ni = 0; ni < FN; ++ni) brow[ni] = wn0 + ni * 16 + l15;

  auto compute = [&](const unsigned char* cA, const unsigned char* cB) {
#pragma unroll
    for (int kh = 0; kh < 2; ++kh) {
      bf16x8 af[FM], bfr[FN];
      if constexpr (AF32) {
        const int Fb = kh * 128 + lg * 32;   // f32 row: 256B, elems [kh*32+lg*8, +8)
#pragma unroll
        for (int mi = 0; mi < FM; ++mi) {
          const int r = arow[mi];
          const unsigned char* p = cA + r * 256;
          const f32x4 lo = *reinterpret_cast<const f32x4*>(p + ((Fb)      ^ ((r & 7) << 4)));
          const f32x4 hi = *reinterpret_cast<const f32x4*>(p + ((Fb + 16) ^ ((r & 7) << 4)));
          bf16x8 a;
          a[0] = (bf16)lo[0]; a[1] = (bf16)lo[1]; a[2] = (bf16)lo[2]; a[3] = (bf16)lo[3];
          a[4] = (bf16)hi[0]; a[5] = (bf16)hi[1]; a[6] = (bf16)hi[2]; a[7] = (bf16)hi[3];
          af[mi] = a;
        }
      } else {
        const int koff = kh * 64 + lg * 16;
#pragma unroll
        for (int mi = 0; mi < FM; ++mi) {
          const int off = (arow[mi] * 128 + koff) ^ ((arow[mi] & 7) << 4);
          af[mi] = *reinterpret_cast<const bf16x8*>(cA + off);
        }
      }
      const int koffB = kh * 64 + lg * 16;
#pragma unroll
      for (int ni = 0; ni < FN; ++ni) {
        const int off = (brow[ni] * 128 + koffB) ^ ((brow[ni] & 7) << 4);
        bfr[ni] = *reinterpret_cast<const bf16x8*>(cB + off);
      }
#pragma unroll
      for (int mi = 0; mi < FM; ++mi)
#pragma unroll
        for (int ni = 0; ni < FN; ++ni)
          acc[mi][ni] = mfma16(af[mi], bfr[ni], acc[mi][ni]);
    }
  };

  if constexpr (AF32) {
    const float* As = (i0 < 512) ? Af + (size_t)i0 * K
                                 : Af2 + (size_t)(i0 - 512) * K;
    for (int kt = 0; kt < K; kt += 64) {
      stage_tile_f32<BM, NT>(As, K, 0, kt, smem, tid);
      stage_tile<BN, NT>(Bt, K, j0, kt, smem + BM * 256, tid);
      __syncthreads();
      compute(smem, smem + BM * 256);
      __syncthreads();
    }
  } else {
    for (int kt = 0; kt < K; kt += 64) {
      stage_tile<BM, NT>(A, K, i0, kt, smem, tid);
      stage_tile<BN, NT>(Bt, K, j0, kt, smem + BM * 128, tid);
      __syncthreads();
      compute(smem, smem + BM * 128);
      __syncthreads();
    }
  }

  if constexpr (MODE == 5) {
    // Re-layout C through LDS one mi-quarter at a time (32 x (BN+4) f32)
    // so each thread owns 16 consecutive cols of one row. xn/xc read as f32.
    // Generic over BN: TPR = BN/16 threads per row, 32 rows per pass.
    constexpr int ES = BN + 4;          // eb row stride (f32)
    constexpr int TPR = BN / 16;        // threads sharing one row
    float* eb = (float*)smem;
#pragma unroll
    for (int mi = 0; mi < FM; ++mi) {
      __syncthreads();
#pragma unroll
      for (int ni = 0; ni < FN; ++ni) {
        const int col = wn0 + ni * 16 + l15;
        const int lr0 = wm * 16 + lg * 4;
#pragma unroll
        for (int r = 0; r < 4; ++r)
          eb[(lr0 + r) * ES + col] = acc[mi][ni][r];
      }
      __syncthreads();
      const int lrow = tid / TPR;                 // 0..31
      const int c0 = (tid % TPR) * 16;            // 0..BN-16
      const int grow = i0 + (lrow >> 4) * 64 + mi * 16 + (lrow & 15);
      const int b = grow >> 5;
      const float* xp = Af2  + (size_t)grow * 2048 + j0 + c0;
      const float* cp = Af   + (size_t)b * 2048 + j0 + c0;
      const float* rp = recon + (size_t)b * 2048 + j0 + c0;
      float nl = 0.f, wa = 0.f;
#pragma unroll
      for (int q4 = 0; q4 < 4; ++q4) {
        const float4 xv = *(const float4*)(xp + q4 * 4);
        const float4 cv = *(const float4*)(cp + q4 * 4);
        const float4 rv = *(const float4*)(rp + q4 * 4);
#pragma unroll
        for (int q = 0; q < 4; ++q) {
          const float xf = ((const float*)&xv)[q];
          const float d = xf - ((const float*)&rv)[q] - eb[lrow * ES + c0 + q4 * 4 + q];
          nl += d * d;
          const float wd = xf - ((const float*)&cv)[q];
          wa += wd * wd;
        }
      }
#pragma unroll
      for (int s = 1; s < TPR; s <<= 1) {
        nl += __shfl_xor(nl, s, 64);
        wa += __shfl_xor(wa, s, 64);
      }
      if ((tid & (TPR - 1)) == 0) {
        atomicAdd(&nloss[grow], nl);
        atomicAdd(&warg[grow], wa);
      }
    }
  } else {
    // C/D frag: row = (lane>>4)*4 + r, col = lane&15
#pragma unroll
    for (int mi = 0; mi < FM; ++mi) {
#pragma unroll
      for (int ni = 0; ni < FN; ++ni) {
#pragma unroll
        for (int r = 0; r < 4; ++r) {
          const int row = i0 + wm0 + mi * 16 + lg * 4 + r;
          const int col = j0 + wn0 + ni * 16 + l15;
          float v = acc[mi][ni][r];
          if constexpr (MODE == 0) {
            v += bias[col];
            out16[(size_t)row * N + col] = (bf16)fmaxf(v, 0.f);
          } else if constexpr (MODE == 1) {
            v += bias[col];
            out32[(size_t)row * N + col] = v;
          } else if constexpr (MODE == 2) {
            v += bias[col];
            out32[(size_t)row * N + col] = v;
            out16[(size_t)row * N + col] = (bf16)fmaxf(v, 0.f);
          } else if constexpr (MODE == 4) {
            const int b = row >> 5;
            const float m = hc[(size_t)b * 512 + col];
            out16[(size_t)row * N + col] = (bf16)(m > 0.f ? v : 0.f);
          }
        }
      }
    }
  }
}

// ---------------------------------------------------------------------------
// All four weight transposes in one launch. in [R][C] f32 -> out [C][R] bf16.
// ---------------------------------------------------------------------------
__global__ void transpose_all_kernel(
    const float* __restrict__ W1, const float* __restrict__ W2,
    const float* __restrict__ V1, const float* __restrict__ V2,
    bf16* __restrict__ W1t, bf16* __restrict__ W2t,
    bf16* __restrict__ V1t, bf16* __restrict__ V2t) {
  int blk = blockIdx.x;
  const float* src; bf16* dst; int R, C, gx;
  if (blk < 1024)      { src = W1; dst = W1t; R = 2048; C = 512;  gx = 16; }
  else if (blk < 1056) { blk -= 1024; src = W2; dst = W2t; R = 512; C = 64;   gx = 2;  }
  else if (blk < 1088) { blk -= 1056; src = V1; dst = V1t; R = 64;  C = 512;  gx = 16; }
  else                 { blk -= 1088; src = V2; dst = V2t; R = 512; C = 2048; gx = 64; }
  __shared__ float t[32][33];
  const int c0 = (blk % gx) * 32, r0 = (blk / gx) * 32;
  const int tx = threadIdx.x, ty = threadIdx.y;   // 32 x 8
#pragma unroll
  for (int i = 0; i < 32; i += 8)
    t[ty + i][tx] = src[(size_t)(r0 + ty + i) * C + c0 + tx];
  __syncthreads();
#pragma unroll
  for (int i = 0; i < 32; i += 8)
    dst[(size_t)(c0 + ty + i) * R + r0 + tx] = (bf16)t[tx][ty + i];
}

// dz = z_nn - z_c (bf16), z_c cast to bf16; also zeroes nloss/warg/out.
__global__ void dz_prep_kernel(const float* __restrict__ z,
                               bf16* __restrict__ dzb,
                               bf16* __restrict__ zcb,
                               float* __restrict__ nw,   // nloss..warg, 32768 f32
                               float* __restrict__ out) {
  const int i = blockIdx.x * 256 + threadIdx.x;   // 16896*64 total
  if (i < 32768) nw[i] = 0.f;
  if (i == 0) out[0] = 0.f;
  const int r = i >> 6, j = i & 63;
  const float v = z[i];
  if (r < 512) {
    zcb[i] = (bf16)v;
  } else {
    const int rn = r - 512;
    const int b = rn >> 5;
    dzb[(size_t)rn * 64 + j] = (bf16)(v - z[(size_t)b * 64 + j]);
  }
}

// out = sum_i exp(-warg[i]/4096) * nloss[i] / 16384
__global__ void finalize_kernel(const float* __restrict__ nloss,
                                const float* __restrict__ warg,
                                float* __restrict__ out) {
  const int i = blockIdx.x * 256 + threadIdx.x;   // 16384 total
  float v = expf(-warg[i] * (1.0f / 4096.0f)) * nloss[i] * (1.0f / 16384.0f);
#pragma unroll
  for (int s = 1; s < 64; s <<= 1) v += __shfl_xor(v, s, 64);
  __shared__ float red[4];
  const int lane = threadIdx.x & 63, w = threadIdx.x >> 6;
  if (lane == 0) red[w] = v;
  __syncthreads();
  if (threadIdx.x == 0) atomicAdd(out, red[0] + red[1] + red[2] + red[3]);
}

// ---------------------------------------------------------------------------
extern "C" void kernel_launch(void* const* d_in, const int* in_sizes, int n_in,
                              void* d_out, int out_size, void* d_ws, size_t ws_size,
                              hipStream_t stream) {
  const float* x_c = (const float*)d_in[0];
  const float* x_nn = (const float*)d_in[1];
  const float* W1 = (const float*)d_in[2];
  const float* b1 = (const float*)d_in[3];
  const float* W2 = (const float*)d_in[4];
  const float* b2 = (const float*)d_in[5];
  const float* V1 = (const float*)d_in[6];
  const float* c1 = (const float*)d_in[7];
  const float* V2 = (const float*)d_in[8];
  const float* c2 = (const float*)d_in[9];
  float* out = (float*)d_out;
  char* ws = (char*)d_ws;

  size_t off = 0;
  auto take = [&](size_t n) { size_t o = off; off += n; return o; };
  bf16*  W1t   = (bf16*) (ws + take((size_t)512 * 2048 * 2));
  bf16*  W2t   = (bf16*) (ws + take((size_t)64 * 512 * 2));
  bf16*  V1t   = (bf16*) (ws + take((size_t)512 * 64 * 2));
  bf16*  V2t   = (bf16*) (ws + take((size_t)2048 * 512 * 2));
  bf16*  h1    = (bf16*) (ws + take((size_t)16896 * 512 * 2));
  float* z     = (float*)(ws + take((size_t)16896 * 64 * 4));
  bf16*  dzb   = (bf16*) (ws + take((size_t)16384 * 64 * 2));
  bf16*  zcb   = (bf16*) (ws + take((size_t)512 * 64 * 2));
  float* hc    = (float*)(ws + take((size_t)512 * 512 * 4));
  bf16*  acb   = (bf16*) (ws + take((size_t)512 * 512 * 2));
  float* recon = (float*)(ws + take((size_t)512 * 2048 * 4));
  bf16*  dab   = (bf16*) (ws + take((size_t)16384 * 512 * 2));
  float* nloss = (float*)(ws + take((size_t)16384 * 4));
  float* warg  = (float*)(ws + take((size_t)16384 * 4));

  // weight transposes
  transpose_all_kernel<<<dim3(2112), dim3(32, 8), 0, stream>>>(
      W1, W2, V1, V2, W1t, W2t, V1t, V2t);

  // GEMM1: h1 = relu([xc;xnn]_f32 @ W1 + b1)  [16896 x 512], K=2048
  // AF32 128x128 tile: x read ONCE as f32 (no cast pass), staged 823 MB,
  // 48KB LDS, grid (4,132)=528, MINW=1. Session optimum (R12/R16: 163.6us).
  gemm_kernel<128, 128, 2, 2, 0, 1, 1><<<dim3(4, 132), dim3(256), 0, stream>>>(
      nullptr, x_c, x_nn, W1t, b1, 16896, 512, 2048,
      nullptr, h1, nullptr, nullptr, nullptr, nullptr);

  // GEMM2: z = h1 @ W2 + b2   [16896 x 64], K=512  (BM=64 -> 264 blocks)
  gemm_kernel<64, 64, 2, 2, 1, 0><<<dim3(1, 264), dim3(256), 0, stream>>>(
      h1, nullptr, nullptr, W2t, b2, 16896, 64, 512,
      z, nullptr, nullptr, nullptr, nullptr, nullptr);

  // dz = z_nn - z_c; cast z_c; zero nloss/warg/out
  dz_prep_kernel<<<dim3(4224), dim3(256), 0, stream>>>(z, dzb, zcb, nloss, out);

  // GEMM3: hc = z_c @ V1 + c1 (f32), acb = relu bf16   [512 x 512], K=64
  gemm_kernel<128, 128, 2, 2, 2, 0><<<dim3(4, 4), dim3(256), 0, stream>>>(
      zcb, nullptr, nullptr, V1t, c1, 512, 512, 64,
      hc, acb, nullptr, nullptr, nullptr, nullptr);

  // GEMM4: recon = acb @ V2 + c2   [512 x 2048], K=512  (BM=64 -> 128 blocks)
  gemm_kernel<64, 128, 2, 2, 1, 0><<<dim3(16, 8), dim3(256), 0, stream>>>(
      acb, nullptr, nullptr, V2t, c2, 512, 2048, 512,
      recon, nullptr, nullptr, nullptr, nullptr, nullptr);

  // GEMM5: dab = (dzb @ V1) * (hc>0)   [16384 x 512], K=64
  gemm_kernel<128, 128, 2, 2, 4, 0><<<dim3(4, 128), dim3(256), 0, stream>>>(
      dzb, nullptr, nullptr, V1t, nullptr, 16384, 512, 64,
      nullptr, dab, hc, nullptr, nullptr, nullptr);

  // GEMM6: Jdz = dab @ V2, fused loss+warg epilogue (f32 x reads)
  // R25: BM=128/BN=256, 512 threads — staged 537 -> 402 MB, grid (8,128)
  // = 1024 blocks, LDS 48KB (R~3). TPR=16 epilogue.
  gemm_kernel<128, 256, 2, 4, 5, 0><<<dim3(8, 128), dim3(512), 0, stream>>>(
      dab, x_c, x_nn, V2t, nullptr, 16384, 2048, 512,
      nullptr, nullptr, nullptr, recon, nloss, warg);

  finalize_kernel<<<dim3(64), dim3(256), 0, stream>>>(nloss, warg, out);
}

// Round 18
// 163.349 us; speedup vs baseline: 1.1456x; 1.1456x over previous
//
#include <hip/hip_runtime.h>
#include <hip/hip_bf16.h>
#include <cstdint>
#include <cstddef>

// B=512, K=32, D=2048, H=512, Z=64; M_all = 16896; M_nn = 16384
#define DEV __device__ __forceinline__

typedef __bf16 bf16;
typedef __bf16 bf16x8 __attribute__((ext_vector_type(8)));
typedef float f32x4 __attribute__((ext_vector_type(4)));

DEV f32x4 mfma16(bf16x8 a, bf16x8 b, f32x4 c) {
  return __builtin_amdgcn_mfma_f32_16x16x32_bf16(a, b, c, 0, 0, 0);
}

DEV void glds16(const void* g, void* l) {
  __builtin_amdgcn_global_load_lds(
      (const __attribute__((address_space(1))) void*)g,
      (__attribute__((address_space(3))) void*)l, 16, 0, 0);
}

// ---------------------------------------------------------------------------
// Stage ROWSx64 bf16 tile (128B rows) -> LDS, XOR swizzle ((row&7)<<4) via
// pre-swizzled global source column; LDS dest linear (glds requirement).
// ---------------------------------------------------------------------------
template<int ROWS, int NT>
DEV void stage_tile(const bf16* __restrict__ src, int ld, int row0, int k0,
                    unsigned char* lds, int tid) {
  constexpr int CALLS = (ROWS * 128) / (NT * 16);
  const int wid = tid >> 6, lane = tid & 63;
#pragma unroll
  for (int c = 0; c < CALLS; ++c) {
    const int obase = c * (NT * 16) + wid * 1024;   // wave-uniform
    const int o = obase + lane * 16;
    const int row = o >> 7;
    const int scb = (o & 127) ^ ((row & 7) << 4);
    glds16(src + (size_t)(row0 + row) * ld + k0 + (scb >> 1), lds + obase);
  }
}

// ---------------------------------------------------------------------------
// Stage ROWSx64 f32 tile (256B rows) -> LDS, 16B-granular XOR swizzle
// ((row&7)<<4). Source column pre-swizzled; LDS dest linear (glds req).
// ---------------------------------------------------------------------------
template<int ROWS, int NT>
DEV void stage_tile_f32(const float* __restrict__ src, int ld, int row0, int k0,
                        unsigned char* lds, int tid) {
  constexpr int CALLS = (ROWS * 256) / (NT * 16);
  const int wid = tid >> 6, lane = tid & 63;
#pragma unroll
  for (int c = 0; c < CALLS; ++c) {
    const int obase = c * (NT * 16) + wid * 1024;   // wave-uniform
    const int o = obase + lane * 16;
    const int row = o >> 8;
    const int scb = (o & 255) ^ ((row & 7) << 4);
    glds16(src + (size_t)(row0 + row) * ld + k0 + (scb >> 2), lds + obase);
  }
}

// ---------------------------------------------------------------------------
// MFMA GEMM: C[M,N] = A[M,K] @ Bt[N,K]^T, bf16 LDS tiles, f32 accum. BK=64.
// AF32=1 (GEMM1): A is f32 [Af rows<512; Af2 rest], staged RAW via glds;
//   fragment load reads two f32x4 + casts to bf16 in-register. x read once.
// FINAL (18 rounds): the glds->LDS 2-barrier family saturates at ~8-13 TB/s
//   aggregate staging delivery (needs residency >= 2-3); time ~ staged/rate.
//   Probed both directions on every axis: GEMM1 tiles 64..512 (128^2 opt),
//   cast-pass/reg-cast/AF32 (AF32 opt), counted-vmcnt/dbuf/BK128/sched_barrier
//   (neutral), split-K x2/x4 (regressed), B-direct-reg (2.9x worse,
//   uncoalesced), GEMM6 re-tile (regressed). This configuration = session
//   optimum, reproduced twice: 163.6 / 163.7 us (from 176.7 baseline).
//   Not a HW roofline (MfmaUtil 12%) — a structure-family plateau; escape
//   requires the 8-phase/256^2 restructure (128^2 quadrant: guide m232 null).
// MODE: 0 relu->bf16; 1 f32+bias; 2 both; 4 mask by hc>0 -> bf16;
//       5 fused loss (nloss/warg via LDS C re-layout, f32 x reads).
// ---------------------------------------------------------------------------
template<int BM, int BN, int WM, int WN, int MODE, int AF32, int MINW = 2>
__global__ __launch_bounds__(WM*WN*64, MINW) void gemm_kernel(
    const bf16* __restrict__ A, const float* __restrict__ Af,
    const float* __restrict__ Af2,
    const bf16* __restrict__ Bt, const float* __restrict__ bias,
    int M, int N, int K,
    float* __restrict__ out32, bf16* __restrict__ out16,
    const float* __restrict__ hc, const float* __restrict__ recon,
    float* __restrict__ nloss, float* __restrict__ warg)
{
  constexpr int NT = WM * WN * 64;
  constexpr int FM = (BM / WM) / 16;
  constexpr int FN = (BN / WN) / 16;
  __shared__ __align__(16) unsigned char smem[AF32 ? (BM * 256 + BN * 128)
                                                   : (BM + BN) * 128];

  const int tid = threadIdx.x, lane = tid & 63, wid = tid >> 6;
  const int wm = wid / WN, wn = wid % WN;
  const int wm0 = wm * (BM / WM), wn0 = wn * (BN / WN);

  // XCD-chunked bijective remap (hw id%8 = XCD).
  int bx = blockIdx.x, by = blockIdx.y;
  {
    const int gx = gridDim.x;
    const int nwg = gx * gridDim.y;
    if ((nwg & 7) == 0) {
      const int fid = by * gx + bx;
      const int cpx = nwg >> 3;
      const int w = (fid & 7) * cpx + (fid >> 3);
      bx = w % gx; by = w / gx;
    }
  }
  const int i0 = by * BM, j0 = bx * BN;
  const int l15 = lane & 15, lg = lane >> 4;

  f32x4 acc[FM][FN] = {};

  int arow[FM], brow[FN];
#pragma unroll
  for (int mi = 0; mi < FM; ++mi) arow[mi] = wm0 + mi * 16 + l15;
#pragma unroll
  for (int ni = 0; ni < FN; ++ni) brow[ni] = wn0 + ni * 16 + l15;

  auto compute = [&](const unsigned char* cA, const unsigned char* cB) {
#pragma unroll
    for (int kh = 0; kh < 2; ++kh) {
      bf16x8 af[FM], bfr[FN];
      if constexpr (AF32) {
        const int Fb = kh * 128 + lg * 32;   // f32 row: 256B, elems [kh*32+lg*8, +8)
#pragma unroll
        for (int mi = 0; mi < FM; ++mi) {
          const int r = arow[mi];
          const unsigned char* p = cA + r * 256;
          const f32x4 lo = *reinterpret_cast<const f32x4*>(p + ((Fb)      ^ ((r & 7) << 4)));
          const f32x4 hi = *reinterpret_cast<const f32x4*>(p + ((Fb + 16) ^ ((r & 7) << 4)));
          bf16x8 a;
          a[0] = (bf16)lo[0]; a[1] = (bf16)lo[1]; a[2] = (bf16)lo[2]; a[3] = (bf16)lo[3];
          a[4] = (bf16)hi[0]; a[5] = (bf16)hi[1]; a[6] = (bf16)hi[2]; a[7] = (bf16)hi[3];
          af[mi] = a;
        }
      } else {
        const int koff = kh * 64 + lg * 16;
#pragma unroll
        for (int mi = 0; mi < FM; ++mi) {
          const int off = (arow[mi] * 128 + koff) ^ ((arow[mi] & 7) << 4);
          af[mi] = *reinterpret_cast<const bf16x8*>(cA + off);
        }
      }
      const int koffB = kh * 64 + lg * 16;
#pragma unroll
      for (int ni = 0; ni < FN; ++ni) {
        const int off = (brow[ni] * 128 + koffB) ^ ((brow[ni] & 7) << 4);
        bfr[ni] = *reinterpret_cast<const bf16x8*>(cB + off);
      }
#pragma unroll
      for (int mi = 0; mi < FM; ++mi)
#pragma unroll
        for (int ni = 0; ni < FN; ++ni)
          acc[mi][ni] = mfma16(af[mi], bfr[ni], acc[mi][ni]);
    }
  };

  if constexpr (AF32) {
    const float* As = (i0 < 512) ? Af + (size_t)i0 * K
                                 : Af2 + (size_t)(i0 - 512) * K;
    for (int kt = 0; kt < K; kt += 64) {
      stage_tile_f32<BM, NT>(As, K, 0, kt, smem, tid);
      stage_tile<BN, NT>(Bt, K, j0, kt, smem + BM * 256, tid);
      __syncthreads();
      compute(smem, smem + BM * 256);
      __syncthreads();
    }
  } else {
    for (int kt = 0; kt < K; kt += 64) {
      stage_tile<BM, NT>(A, K, i0, kt, smem, tid);
      stage_tile<BN, NT>(Bt, K, j0, kt, smem + BM * 128, tid);
      __syncthreads();
      compute(smem, smem + BM * 128);
      __syncthreads();
    }
  }

  if constexpr (MODE == 5) {
    // Re-layout C through LDS one mi-quarter at a time (32 x (BN+4) f32)
    // so each thread owns 16 consecutive cols of one row. xn/xc read as f32.
    // Generic over BN: TPR = BN/16 threads per row, 32 rows per pass.
    constexpr int ES = BN + 4;          // eb row stride (f32)
    constexpr int TPR = BN / 16;        // threads sharing one row
    float* eb = (float*)smem;
#pragma unroll
    for (int mi = 0; mi < FM; ++mi) {
      __syncthreads();
#pragma unroll
      for (int ni = 0; ni < FN; ++ni) {
        const int col = wn0 + ni * 16 + l15;
        const int lr0 = wm * 16 + lg * 4;
#pragma unroll
        for (int r = 0; r < 4; ++r)
          eb[(lr0 + r) * ES + col] = acc[mi][ni][r];
      }
      __syncthreads();
      const int lrow = tid / TPR;                 // 0..31
      const int c0 = (tid % TPR) * 16;            // 0..BN-16
      const int grow = i0 + (lrow >> 4) * 64 + mi * 16 + (lrow & 15);
      const int b = grow >> 5;
      const float* xp = Af2  + (size_t)grow * 2048 + j0 + c0;
      const float* cp = Af   + (size_t)b * 2048 + j0 + c0;
      const float* rp = recon + (size_t)b * 2048 + j0 + c0;
      float nl = 0.f, wa = 0.f;
#pragma unroll
      for (int q4 = 0; q4 < 4; ++q4) {
        const float4 xv = *(const float4*)(xp + q4 * 4);
        const float4 cv = *(const float4*)(cp + q4 * 4);
        const float4 rv = *(const float4*)(rp + q4 * 4);
#pragma unroll
        for (int q = 0; q < 4; ++q) {
          const float xf = ((const float*)&xv)[q];
          const float d = xf - ((const float*)&rv)[q] - eb[lrow * ES + c0 + q4 * 4 + q];
          nl += d * d;
          const float wd = xf - ((const float*)&cv)[q];
          wa += wd * wd;
        }
      }
#pragma unroll
      for (int s = 1; s < TPR; s <<= 1) {
        nl += __shfl_xor(nl, s, 64);
        wa += __shfl_xor(wa, s, 64);
      }
      if ((tid & (TPR - 1)) == 0) {
        atomicAdd(&nloss[grow], nl);
        atomicAdd(&warg[grow], wa);
      }
    }
  } else {
    // C/D frag: row = (lane>>4)*4 + r, col = lane&15
#pragma unroll
    for (int mi = 0; mi < FM; ++mi) {
#pragma unroll
      for (int ni = 0; ni < FN; ++ni) {
#pragma unroll
        for (int r = 0; r < 4; ++r) {
          const int row = i0 + wm0 + mi * 16 + lg * 4 + r;
          const int col = j0 + wn0 + ni * 16 + l15;
          float v = acc[mi][ni][r];
          if constexpr (MODE == 0) {
            v += bias[col];
            out16[(size_t)row * N + col] = (bf16)fmaxf(v, 0.f);
          } else if constexpr (MODE == 1) {
            v += bias[col];
            out32[(size_t)row * N + col] = v;
          } else if constexpr (MODE == 2) {
            v += bias[col];
            out32[(size_t)row * N + col] = v;
            out16[(size_t)row * N + col] = (bf16)fmaxf(v, 0.f);
          } else if constexpr (MODE == 4) {
            const int b = row >> 5;
            const float m = hc[(size_t)b * 512 + col];
            out16[(size_t)row * N + col] = (bf16)(m > 0.f ? v : 0.f);
          }
        }
      }
    }
  }
}

// ---------------------------------------------------------------------------
// All four weight transposes in one launch. in [R][C] f32 -> out [C][R] bf16.
// ---------------------------------------------------------------------------
__global__ void transpose_all_kernel(
    const float* __restrict__ W1, const float* __restrict__ W2,
    const float* __restrict__ V1, const float* __restrict__ V2,
    bf16* __restrict__ W1t, bf16* __restrict__ W2t,
    bf16* __restrict__ V1t, bf16* __restrict__ V2t) {
  int blk = blockIdx.x;
  const float* src; bf16* dst; int R, C, gx;
  if (blk < 1024)      { src = W1; dst = W1t; R = 2048; C = 512;  gx = 16; }
  else if (blk < 1056) { blk -= 1024; src = W2; dst = W2t; R = 512; C = 64;   gx = 2;  }
  else if (blk < 1088) { blk -= 1056; src = V1; dst = V1t; R = 64;  C = 512;  gx = 16; }
  else                 { blk -= 1088; src = V2; dst = V2t; R = 512; C = 2048; gx = 64; }
  __shared__ float t[32][33];
  const int c0 = (blk % gx) * 32, r0 = (blk / gx) * 32;
  const int tx = threadIdx.x, ty = threadIdx.y;   // 32 x 8
#pragma unroll
  for (int i = 0; i < 32; i += 8)
    t[ty + i][tx] = src[(size_t)(r0 + ty + i) * C + c0 + tx];
  __syncthreads();
#pragma unroll
  for (int i = 0; i < 32; i += 8)
    dst[(size_t)(c0 + ty + i) * R + r0 + tx] = (bf16)t[tx][ty + i];
}

// dz = z_nn - z_c (bf16), z_c cast to bf16; also zeroes nloss/warg/out.
__global__ void dz_prep_kernel(const float* __restrict__ z,
                               bf16* __restrict__ dzb,
                               bf16* __restrict__ zcb,
                               float* __restrict__ nw,   // nloss..warg, 32768 f32
                               float* __restrict__ out) {
  const int i = blockIdx.x * 256 + threadIdx.x;   // 16896*64 total
  if (i < 32768) nw[i] = 0.f;
  if (i == 0) out[0] = 0.f;
  const int r = i >> 6, j = i & 63;
  const float v = z[i];
  if (r < 512) {
    zcb[i] = (bf16)v;
  } else {
    const int rn = r - 512;
    const int b = rn >> 5;
    dzb[(size_t)rn * 64 + j] = (bf16)(v - z[(size_t)b * 64 + j]);
  }
}

// out = sum_i exp(-warg[i]/4096) * nloss[i] / 16384
__global__ void finalize_kernel(const float* __restrict__ nloss,
                                const float* __restrict__ warg,
                                float* __restrict__ out) {
  const int i = blockIdx.x * 256 + threadIdx.x;   // 16384 total
  float v = expf(-warg[i] * (1.0f / 4096.0f)) * nloss[i] * (1.0f / 16384.0f);
#pragma unroll
  for (int s = 1; s < 64; s <<= 1) v += __shfl_xor(v, s, 64);
  __shared__ float red[4];
  const int lane = threadIdx.x & 63, w = threadIdx.x >> 6;
  if (lane == 0) red[w] = v;
  __syncthreads();
  if (threadIdx.x == 0) atomicAdd(out, red[0] + red[1] + red[2] + red[3]);
}

// ---------------------------------------------------------------------------
extern "C" void kernel_launch(void* const* d_in, const int* in_sizes, int n_in,
                              void* d_out, int out_size, void* d_ws, size_t ws_size,
                              hipStream_t stream) {
  const float* x_c = (const float*)d_in[0];
  const float* x_nn = (const float*)d_in[1];
  const float* W1 = (const float*)d_in[2];
  const float* b1 = (const float*)d_in[3];
  const float* W2 = (const float*)d_in[4];
  const float* b2 = (const float*)d_in[5];
  const float* V1 = (const float*)d_in[6];
  const float* c1 = (const float*)d_in[7];
  const float* V2 = (const float*)d_in[8];
  const float* c2 = (const float*)d_in[9];
  float* out = (float*)d_out;
  char* ws = (char*)d_ws;

  size_t off = 0;
  auto take = [&](size_t n) { size_t o = off; off += n; return o; };
  bf16*  W1t   = (bf16*) (ws + take((size_t)512 * 2048 * 2));
  bf16*  W2t   = (bf16*) (ws + take((size_t)64 * 512 * 2));
  bf16*  V1t   = (bf16*) (ws + take((size_t)512 * 64 * 2));
  bf16*  V2t   = (bf16*) (ws + take((size_t)2048 * 512 * 2));
  bf16*  h1    = (bf16*) (ws + take((size_t)16896 * 512 * 2));
  float* z     = (float*)(ws + take((size_t)16896 * 64 * 4));
  bf16*  dzb   = (bf16*) (ws + take((size_t)16384 * 64 * 2));
  bf16*  zcb   = (bf16*) (ws + take((size_t)512 * 64 * 2));
  float* hc    = (float*)(ws + take((size_t)512 * 512 * 4));
  bf16*  acb   = (bf16*) (ws + take((size_t)512 * 512 * 2));
  float* recon = (float*)(ws + take((size_t)512 * 2048 * 4));
  bf16*  dab   = (bf16*) (ws + take((size_t)16384 * 512 * 2));
  float* nloss = (float*)(ws + take((size_t)16384 * 4));
  float* warg  = (float*)(ws + take((size_t)16384 * 4));

  // weight transposes
  transpose_all_kernel<<<dim3(2112), dim3(32, 8), 0, stream>>>(
      W1, W2, V1, V2, W1t, W2t, V1t, V2t);

  // GEMM1: h1 = relu([xc;xnn]_f32 @ W1 + b1)  [16896 x 512], K=2048
  // AF32 128x128 tile: x read ONCE as f32 (no cast pass), staged 823 MB,
  // 48KB LDS, grid (4,132)=528, MINW=1. Session optimum (R12/R16: 163.6us).
  gemm_kernel<128, 128, 2, 2, 0, 1, 1><<<dim3(4, 132), dim3(256), 0, stream>>>(
      nullptr, x_c, x_nn, W1t, b1, 16896, 512, 2048,
      nullptr, h1, nullptr, nullptr, nullptr, nullptr);

  // GEMM2: z = h1 @ W2 + b2   [16896 x 64], K=512  (BM=64 -> 264 blocks)
  gemm_kernel<64, 64, 2, 2, 1, 0><<<dim3(1, 264), dim3(256), 0, stream>>>(
      h1, nullptr, nullptr, W2t, b2, 16896, 64, 512,
      z, nullptr, nullptr, nullptr, nullptr, nullptr);

  // dz = z_nn - z_c; cast z_c; zero nloss/warg/out
  dz_prep_kernel<<<dim3(4224), dim3(256), 0, stream>>>(z, dzb, zcb, nloss, out);

  // GEMM3: hc = z_c @ V1 + c1 (f32), acb = relu bf16   [512 x 512], K=64
  gemm_kernel<128, 128, 2, 2, 2, 0><<<dim3(4, 4), dim3(256), 0, stream>>>(
      zcb, nullptr, nullptr, V1t, c1, 512, 512, 64,
      hc, acb, nullptr, nullptr, nullptr, nullptr);

  // GEMM4: recon = acb @ V2 + c2   [512 x 2048], K=512  (BM=64 -> 128 blocks)
  gemm_kernel<64, 128, 2, 2, 1, 0><<<dim3(16, 8), dim3(256), 0, stream>>>(
      acb, nullptr, nullptr, V2t, c2, 512, 2048, 512,
      recon, nullptr, nullptr, nullptr, nullptr, nullptr);

  // GEMM5: dab = (dzb @ V1) * (hc>0)   [16384 x 512], K=64
  gemm_kernel<128, 128, 2, 2, 4, 0><<<dim3(4, 128), dim3(256), 0, stream>>>(
      dzb, nullptr, nullptr, V1t, nullptr, 16384, 512, 64,
      nullptr, dab, hc, nullptr, nullptr, nullptr);

  // GEMM6: Jdz = dab @ V2, fused loss+warg epilogue (f32 x reads)
  // 128x128 (TPR=8 epilogue == original verified code), grid (16,128)=2048.
  gemm_kernel<128, 128, 2, 2, 5, 0><<<dim3(16, 128), dim3(256), 0, stream>>>(
      dab, x_c, x_nn, V2t, nullptr, 16384, 2048, 512,
      nullptr, nullptr, nullptr, recon, nloss, warg);

  finalize_kernel<<<dim3(64), dim3(256), 0, stream>>>(nloss, warg, out);
}